// Round 11
// baseline (393.344 us; speedup 1.0000x reference)
//
#include <hip/hip_runtime.h>
#include <hip/hip_fp16.h>

#define HASH_PRIME 5099
#define NE 64
#define ND 512
#define NF 1792
#define NS 32768
#define CAP 512

typedef unsigned short u16;
typedef __attribute__((ext_vector_type(8))) short bf16x8;
typedef __attribute__((ext_vector_type(4))) float f32x4;

__device__ __forceinline__ u16 f2bf(float f) {
  union { float f; unsigned u; } v; v.f = f;
  return (u16)((v.u + 0x7FFFu + ((v.u >> 16) & 1u)) >> 16);
}
__device__ __forceinline__ unsigned pkbf2(float a, float b) {
  return (unsigned)f2bf(a) | ((unsigned)f2bf(b) << 16);
}

__device__ __forceinline__ void gld16(const void* g, void* l) {
  __builtin_amdgcn_global_load_lds(
      (const __attribute__((address_space(1))) unsigned int*)(uintptr_t)g,
      (__attribute__((address_space(3))) unsigned int*)(uintptr_t)l,
      16, 0, 0);
}

// ---------------- routing ----------------
__global__ __launch_bounds__(512) void route1(const int* __restrict__ tok,
                                              int* __restrict__ rank_local,
                                              int* __restrict__ hist) {
  __shared__ int se[512];
  __shared__ int h[NE];
  int b = blockIdx.x, t = threadIdx.x;
  int s = b * 512 + t;
  int e = (tok[s] % HASH_PRIME) % NE;
  se[t] = e;
  if (t < NE) h[t] = 0;
  __syncthreads();
  int cnt = 0;
  for (int j = 0; j < t; ++j) cnt += (se[j] == e);
  rank_local[s] = cnt;
  atomicAdd(&h[e], 1);
  __syncthreads();
  if (t < NE) hist[b * NE + t] = h[t];
}

__global__ __launch_bounds__(512) void route2(const int* __restrict__ tok,
                                              const int* __restrict__ rank_local,
                                              const int* __restrict__ hist,
                                              int* __restrict__ slot_src) {
  __shared__ int off[NE];
  int b = blockIdx.x, t = threadIdx.x;
  if (t < NE) {
    int o = 0;
    for (int bb = 0; bb < b; ++bb) o += hist[bb * NE + t];
    off[t] = o;
  }
  __syncthreads();
  int s = b * 512 + t;
  int e = (tok[s] % HASH_PRIME) % NE;
  int pos = off[e] + rank_local[s];
  if (pos < CAP) slot_src[e * CAP + pos] = s;
}

// ---------------- dispatch: gather X -> bf16 Xd[E,CAP,D] ----------------
__global__ __launch_bounds__(256) void dispatchx(const float* __restrict__ x,
                                                 const int* __restrict__ slot_src,
                                                 u16* __restrict__ Xd) {
  int b = blockIdx.x;
  int t = threadIdx.x;
  int row = b * 4 + (t >> 6);
  int col = (t & 63) * 8;
  int s = slot_src[row];
  uint4 w = make_uint4(0u, 0u, 0u, 0u);
  if (s >= 0) {
    const float4* p = (const float4*)(x + (size_t)s * ND + col);
    float4 a = p[0], c = p[1];
    w.x = pkbf2(a.x, a.y); w.y = pkbf2(a.z, a.w);
    w.z = pkbf2(c.x, c.y); w.w = pkbf2(c.z, c.w);
  }
  *(uint4*)(Xd + (size_t)row * ND + col) = w;
}

// ---------------- 2-phase pipelined GEMM core (r11) ----------------
// 256x256 tile, BK=64 K-tiles, 8 waves (2m x 4n), 512 threads.
// LDS: A,B each [2 slots][256 rows][64 k] bf16; ONE SLOT = 32768 B = 16384 hw.
// Swizzle: halfword idx = row*64 + ((k>>3) ^ (row&7))*8 + (k&7).
// Per K-tile: 2 phases (m-half). B fragments (8 b128) read ONCE in p0 and
// held in regs across both phases -> 24 b128 reads + 4 barriers per K-tile
// (r10 had 32 reads + 8 barriers; its read-segment dominated MFMA 1024:620).
// Per-phase: 32 MFMA.
//
// WAIT LEDGER (order-independent within phases; fenced barriers pin phase
// boundaries; all waits sit IMMEDIATELY BEFORE a barrier since vmcnt is
// per-wave and staging is cooperative):
//  p0 issues: 2 GLDA (rows 0/128 of kt+1) + 8 B-loads (kt+1)
//  p1 issues: 2 GLDA (rows 64/192 of kt+1)
//  VMW(10) at p0-end: outstanding <= p1(kt-1).2 + p0(kt).10 = 12 -> drains
//    p1(kt-1)'s GLDAs = A rows 64/192 of slot(kt), read at p1(kt).
//  VMW(2) at p1-end: outstanding <= p0(kt).10 + p1(kt).2 = 12 -> drains all
//    of p0(kt) = A rows 0/128 of slot(kt+1), read at p0(kt+1).
//  ds_write visibility: WRB; BAR; own-wave LGKM0; MFMA; BAR; readers next.
//  VMW(0) after loop: no gld16 outlives the block.

#define GDECL \
  __shared__ u16 AsH[2 * 256 * 64]; \
  __shared__ u16 BsH[2 * 256 * 64]; \
  const int t = threadIdx.x; \
  const int l = t & 63; \
  const int w = t >> 6; \
  const int wm = w >> 2; \
  const int wn = w & 3; \
  const int lrow = l & 15; \
  const int kb = l >> 4; \
  const int rsw0_ = ((kb) ^ (l & 7)) * 8; \
  const int rsw1_ = ((4 + kb) ^ (l & 7)) * 8; \
  const int arow_ = w * 8 + (l >> 3); \
  const int asw_ = ((l & 7) ^ (l >> 3)) * 8; \
  const int brow_ = (t >> 7) * 64 + ((t >> 2) & 31); \
  const int bkq_ = t & 3; \
  const int bsa_ = ((bkq_ * 2) ^ (brow_ & 7)) * 8; \
  const int bsb_ = ((bkq_ * 2 + 1) ^ (brow_ & 7)) * 8;

#define GLDA(sl, rbase, ktS, abase, AST) do { \
  const u16* g_ = (abase) + (size_t)((rbase) + arow_) * (AST) + (size_t)(ktS) * 64 + asw_; \
  gld16(g_, (char*)AsH + (sl) * 32768 + (rbase) * 128 + t * 16); \
} while (0)

#define LOADB(dst, ktS, u, bbase, BST) do { \
  const float4* p_ = (const float4*)((bbase) + (size_t)(brow_ + (u) * 32) * (BST) + (size_t)(ktS) * 64 + bkq_ * 16); \
  dst[0] = p_[0]; dst[1] = p_[1]; dst[2] = p_[2]; dst[3] = p_[3]; \
} while (0)

#define WRB(sl, u, src) do { \
  uint4 w0_, w1_; \
  w0_.x = pkbf2(src[0].x, src[0].y); w0_.y = pkbf2(src[0].z, src[0].w); \
  w0_.z = pkbf2(src[1].x, src[1].y); w0_.w = pkbf2(src[1].z, src[1].w); \
  w1_.x = pkbf2(src[2].x, src[2].y); w1_.y = pkbf2(src[2].z, src[2].w); \
  w1_.z = pkbf2(src[3].x, src[3].y); w1_.w = pkbf2(src[3].z, src[3].w); \
  *(uint4*)&BsH[(sl) * 16384 + (brow_ + (u) * 32) * 64 + bsa_] = w0_; \
  *(uint4*)&BsH[(sl) * 16384 + (brow_ + (u) * 32) * 64 + bsb_] = w1_; \
} while (0)

#define RDA(mh, slotH) do { \
  _Pragma("unroll") for (int ml_ = 0; ml_ < 4; ++ml_) { \
    const int r_ = wm * 128 + ((mh) * 4 + ml_) * 16 + lrow; \
    af[ml_][0] = *(const bf16x8*)&AsH[(slotH) + r_ * 64 + rsw0_]; \
    af[ml_][1] = *(const bf16x8*)&AsH[(slotH) + r_ * 64 + rsw1_]; \
  } \
} while (0)

#define RDB4(slotH) do { \
  _Pragma("unroll") for (int nf_ = 0; nf_ < 4; ++nf_) { \
    const int r_ = wn * 64 + nf_ * 16 + lrow; \
    bf[nf_][0] = *(const bf16x8*)&BsH[(slotH) + r_ * 64 + rsw0_]; \
    bf[nf_][1] = *(const bf16x8*)&BsH[(slotH) + r_ * 64 + rsw1_]; \
  } \
} while (0)

#define MFMA32(mh) do { \
  _Pragma("unroll") for (int ml_ = 0; ml_ < 4; ++ml_) \
    _Pragma("unroll") for (int nf_ = 0; nf_ < 4; ++nf_) \
      _Pragma("unroll") for (int ks_ = 0; ks_ < 2; ++ks_) \
        acc[(mh) * 4 + ml_][nf_] = __builtin_amdgcn_mfma_f32_16x16x32_bf16( \
            af[ml_][ks_], bf[nf_][ks_], acc[(mh) * 4 + ml_][nf_], 0, 0, 0); \
} while (0)

#define FENCE() asm volatile("" ::: "memory")
#define BAR()  do { FENCE(); __builtin_amdgcn_s_barrier(); FENCE(); } while (0)
#define LGKM0() asm volatile("s_waitcnt lgkmcnt(0)" ::: "memory")
#define VMW(n) asm volatile("s_waitcnt vmcnt(" #n ")" ::: "memory")

#define GEMM_CORE(NKT, abase, AST, bbase, BST) \
  f32x4 acc[8][4]; \
  _Pragma("unroll") for (int m_ = 0; m_ < 8; ++m_) \
    _Pragma("unroll") for (int n_ = 0; n_ < 4; ++n_) \
      acc[m_][n_] = (f32x4){0.f, 0.f, 0.f, 0.f}; \
  bf16x8 af[4][2]; \
  bf16x8 bf[4][2]; \
  float4 fq[4], fu1[4]; \
  /* prologue: stage K-tile 0 (A via gld_lds, B via reg+cvt), fully drained */ \
  GLDA(0, 0, 0, abase, AST); GLDA(0, 128, 0, abase, AST); \
  GLDA(0, 64, 0, abase, AST); GLDA(0, 192, 0, abase, AST); \
  LOADB(fq, 0, 0, bbase, BST); \
  LOADB(fu1, 0, 1, bbase, BST); \
  WRB(0, 0, fq); WRB(0, 1, fu1); \
  VMW(0); \
  LGKM0(); \
  BAR(); \
  _Pragma("unroll 2") \
  for (int kt = 0; kt < (NKT); ++kt) { \
    const int slot = kt & 1, ss_ = slot ^ 1; \
    const int slotH = slot * 16384; \
    const int ktS = (kt + 1 < (NKT)) ? kt + 1 : 0; \
    { /* p0: m-half 0 x all n */ \
      RDA(0, slotH); RDB4(slotH); \
      GLDA(ss_, 0, ktS, abase, AST); GLDA(ss_, 128, ktS, abase, AST); \
      LOADB(fq, ktS, 0, bbase, BST); \
      LOADB(fu1, ktS, 1, bbase, BST); \
      BAR(); LGKM0(); \
      __builtin_amdgcn_s_setprio(1); MFMA32(0); __builtin_amdgcn_s_setprio(0); \
      VMW(10); /* A rows 64/192 of slot(kt) landed (staged by p1(kt-1)) */ \
      BAR(); \
    } \
    { /* p1: m-half 1 x all n (bf held in regs from p0) */ \
      RDA(1, slotH); \
      GLDA(ss_, 64, ktS, abase, AST); GLDA(ss_, 192, ktS, abase, AST); \
      WRB(ss_, 0, fq); WRB(ss_, 1, fu1); \
      BAR(); LGKM0(); \
      __builtin_amdgcn_s_setprio(1); MFMA32(1); __builtin_amdgcn_s_setprio(0); \
      VMW(2); /* all of p0(kt) drained: A rows 0/128 of slot(kt+1) landed */ \
      BAR(); \
    } \
  } \
  VMW(0); /* no gld16 may outlive this block (LDS reuse by next WG) */

// ---------------- G1: H = relu(Xd Wk^T)^2, bf16 ----------------
__global__ __launch_bounds__(512, 2) void g1(const u16* __restrict__ Xd,
                                             const float* __restrict__ Wk,
                                             u16* __restrict__ H) {
  GDECL
  const int wg = (blockIdx.x & 7) * 112 + (blockIdx.x >> 3);  // 896 blocks
  const int e = wg / 14, rem = wg % 14;
  const int m0 = (rem & 1) * 256;
  const int n0 = (rem >> 1) * 256;
  const u16*  abase = Xd + ((size_t)e * CAP + m0) * ND;
  const float* bbase = Wk + ((size_t)e * NF + n0) * ND;
  GEMM_CORE(8, abase, ND, bbase, ND)

  #pragma unroll
  for (int m = 0; m < 8; ++m) {
    #pragma unroll
    for (int i = 0; i < 4; ++i) {
      int r = m0 + wm * 128 + m * 16 + (l >> 4) * 4 + i;
      size_t base = ((size_t)e * CAP + r) * NF + n0 + wn * 64 + lrow;
      #pragma unroll
      for (int n = 0; n < 4; ++n) {
        float v = acc[m][n][i];
        v = v > 0.f ? v * v : 0.f;
        H[base + n * 16] = f2bf(v);
      }
    }
  }
}

// ---------------- G2a: R = sigmoid(Xd Wr^T), fp16 ----------------
__global__ __launch_bounds__(512, 2) void g2a(const u16* __restrict__ Xd,
                                              const float* __restrict__ Wr,
                                              __half* __restrict__ R) {
  GDECL
  const int wg = (blockIdx.x & 7) * 32 + (blockIdx.x >> 3);  // 256 blocks
  const int e = wg >> 2, rem = wg & 3;
  const int m0 = (rem & 1) * 256;
  const int n0 = (rem >> 1) * 256;
  const u16*  abase = Xd + ((size_t)e * CAP + m0) * ND;
  const float* bbase = Wr + ((size_t)e * ND + n0) * ND;
  GEMM_CORE(8, abase, ND, bbase, ND)

  #pragma unroll
  for (int m = 0; m < 8; ++m) {
    #pragma unroll
    for (int i = 0; i < 4; ++i) {
      int r = m0 + wm * 128 + m * 16 + (l >> 4) * 4 + i;
      size_t base = ((size_t)e * CAP + r) * ND + n0 + wn * 64 + lrow;
      #pragma unroll
      for (int n = 0; n < 4; ++n) {
        float s = 1.f / (1.f + __expf(-acc[m][n][i]));
        R[base + n * 16] = __float2half(s);
      }
    }
  }
}

// ---------------- G2b: out = R * (H Wv^T), scatter ----------------
__global__ __launch_bounds__(512, 2) void g2b(const u16* __restrict__ H,
                                              const float* __restrict__ Wv,
                                              const __half* __restrict__ R,
                                              const int* __restrict__ slot_src,
                                              float* __restrict__ out) {
  GDECL
  const int wg = (blockIdx.x & 7) * 32 + (blockIdx.x >> 3);  // 256 blocks
  const int e = wg >> 2, rem = wg & 3;
  const int m0 = (rem & 1) * 256;
  const int n0 = (rem >> 1) * 256;
  const u16*  abase = H  + ((size_t)e * CAP + m0) * NF;
  const float* bbase = Wv + ((size_t)e * ND + n0) * NF;
  GEMM_CORE(28, abase, NF, bbase, NF)

  #pragma unroll
  for (int m = 0; m < 8; ++m) {
    #pragma unroll
    for (int i = 0; i < 4; ++i) {
      int rl = m0 + wm * 128 + m * 16 + (l >> 4) * 4 + i;
      int s = slot_src[e * CAP + rl];
      if (s >= 0) {
        const __half* rp = R + ((size_t)e * CAP + rl) * ND + n0 + wn * 64 + lrow;
        float* op = out + (size_t)s * ND + n0 + wn * 64 + lrow;
        #pragma unroll
        for (int n = 0; n < 4; ++n) {
          op[n * 16] = __half2float(rp[n * 16]) * acc[m][n][i];
        }
      }
    }
  }
}

extern "C" void kernel_launch(void* const* d_in, const int* in_sizes, int n_in,
                              void* d_out, int out_size, void* d_ws, size_t ws_size,
                              hipStream_t stream) {
  const float* x   = (const float*)d_in[0];
  const int*   tok = (const int*)d_in[1];
  const float* Wk  = (const float*)d_in[2];
  const float* Wr  = (const float*)d_in[3];
  const float* Wv  = (const float*)d_in[4];
  float* out = (float*)d_out;

  char* ws = (char*)d_ws;
  int*    slot_src   = (int*)ws;
  int*    rank_local = (int*)(ws + 131072);
  int*    hist       = (int*)(ws + 262144);
  u16*    Xd         = (u16*)(ws + (1 << 20));
  __half* R          = (__half*)(ws + 34603008);
  u16*    Hbuf       = (u16*)(ws + 68157440);

  (void)hipMemsetAsync(d_out, 0, (size_t)out_size * sizeof(float), stream);
  (void)hipMemsetAsync(slot_src, 0xFF, NE * CAP * sizeof(int), stream);
  route1<<<64, 512, 0, stream>>>(tok, rank_local, hist);
  route2<<<64, 512, 0, stream>>>(tok, rank_local, hist, slot_src);
  dispatchx<<<NS / 4, 256, 0, stream>>>(x, slot_src, Xd);
  g1 <<<896, 512, 0, stream>>>(Xd, Wk, Hbuf);
  g2a<<<256, 512, 0, stream>>>(Xd, Wr, R);
  g2b<<<256, 512, 0, stream>>>(Hbuf, Wv, R, slot_src, out);
}